// Round 4
// 501.782 us; speedup vs baseline: 1.1103x; 1.1103x over previous
//
#include <hip/hip_runtime.h>
#include <hip/hip_bf16.h>
#include <math.h>

// Problem constants (B=2,S=2048 -> T=4096, H=1024, I=2048, E=8, top-2)
#define T_TOK 4096
#define H_DIM 1024
#define I_DIM 2048
#define E_NUM 8

typedef __bf16 bf16x8 __attribute__((ext_vector_type(8)));
typedef float  f32x4  __attribute__((ext_vector_type(4)));
typedef unsigned short u16x4 __attribute__((ext_vector_type(4)));
typedef unsigned short u16x8 __attribute__((ext_vector_type(8)));

// ---- helpers -------------------------------------------------------------
__device__ inline void gll16(const void* g, void* l) {
    __builtin_amdgcn_global_load_lds(
        (const __attribute__((address_space(1))) void*)g,
        (__attribute__((address_space(3))) void*)l, 16, 0, 0);
}

__device__ inline unsigned short f2bf(float f) {
    union { float f; unsigned u; } v; v.f = f;
    unsigned r = v.u + 0x7FFF + ((v.u >> 16) & 1);   // RNE
    return (unsigned short)(r >> 16);
}

// Stage a 128-row x 64-col bf16 tile (16 KB) into LDS via global_load_lds.
// Physical LDS layout: row-major, 128 B/row; physical k-group g holds logical
// k-group g ^ (row & 7)  (XOR swizzle -> spread banks on frag reads).
__device__ inline void stage_tile64(const unsigned short* gbase, size_t stride_elems,
                                    int k0, char* smbase, int tid, int wv) {
#pragma unroll
    for (int it = 0; it < 4; ++it) {
        int idx = it * 256 + tid;            // 0..1023, 16 B each
        int r   = idx >> 3;                  // tile row 0..127
        int kg  = (idx & 7) ^ (r & 7);       // logical k-group for this slot
        const void* g = gbase + (size_t)r * stride_elems + k0 + kg * 8;
        void* l = smbase + it * 4096 + wv * 1024;   // wave-uniform base
        gll16(g, l);
    }
}

__device__ inline bf16x8 frag_ld64(const char* smbase, int row, int kg_log) {
    int kg = kg_log ^ (row & 7);
    return *(const bf16x8*)(smbase + row * 128 + kg * 16);
}

// ---------------- Router ----------------
__global__ __launch_bounds__(256) void router_kernel(
    const float* __restrict__ x, const float* __restrict__ gw,
    float* __restrict__ logits_out, int* __restrict__ counts,
    int* __restrict__ tok_list, float* __restrict__ w_list,
    int* __restrict__ tslot)
{
    int wave = threadIdx.x >> 6;
    int lane = threadIdx.x & 63;
    int t = blockIdx.x * 4 + wave;
    if (t >= T_TOK) return;

    float xs[16];
#pragma unroll
    for (int i = 0; i < 16; ++i) xs[i] = x[(size_t)t * H_DIM + i * 64 + lane];

    float lg[E_NUM];
#pragma unroll
    for (int e = 0; e < E_NUM; ++e) {
        float acc = 0.f;
#pragma unroll
        for (int i = 0; i < 16; ++i) acc += xs[i] * gw[e * H_DIM + i * 64 + lane];
#pragma unroll
        for (int off = 32; off >= 1; off >>= 1) acc += __shfl_xor(acc, off, 64);
        lg[e] = acc;
    }

    if (lane == 0) {
#pragma unroll
        for (int e = 0; e < E_NUM; ++e) logits_out[(size_t)t * E_NUM + e] = lg[e];
        float m = lg[0];
        for (int e = 1; e < E_NUM; ++e) m = fmaxf(m, lg[e]);
        float p[E_NUM]; float s = 0.f;
        for (int e = 0; e < E_NUM; ++e) { p[e] = expf(lg[e] - m); s += p[e]; }
        float invs = 1.f / s;
        for (int e = 0; e < E_NUM; ++e) p[e] *= invs;
        int i0 = 0; float p0 = p[0];
        for (int e = 1; e < E_NUM; ++e) if (p[e] > p0) { p0 = p[e]; i0 = e; }
        int i1 = -1; float p1 = -1.f;
        for (int e = 0; e < E_NUM; ++e) { if (e == i0) continue; if (p[e] > p1) { p1 = p[e]; i1 = e; } }
        float inv = 1.f / (p0 + p1);
        int pos0 = atomicAdd(&counts[i0], 1);
        tok_list[i0 * T_TOK + pos0] = t; w_list[i0 * T_TOK + pos0] = p0 * inv;
        int pos1 = atomicAdd(&counts[i1], 1);
        tok_list[i1 * T_TOK + pos1] = t; w_list[i1 * T_TOK + pos1] = p1 * inv;
        tslot[t * 2 + 0] = i0 * T_TOK + pos0;   // T_TOK = 4096 = 2^12
        tslot[t * 2 + 1] = i1 * T_TOK + pos1;
    }
}

// ---------------- Padded offsets (128-aligned per expert) ----------------
__global__ void offsets_kernel(const int* __restrict__ counts, int* __restrict__ poff)
{
    if (threadIdx.x == 0 && blockIdx.x == 0) {
        int s = 0;
        for (int e = 0; e < E_NUM; ++e) { poff[e] = s; s += ((counts[e] + 127) >> 7) << 7; }
    }
}

// ---------------- Gather x rows -> xg (bf16, padded slots) ----------------
__global__ __launch_bounds__(256) void gather_x(
    const float* __restrict__ x, const int* __restrict__ counts,
    const int* __restrict__ poff, const int* __restrict__ tok_list,
    unsigned short* __restrict__ xg)
{
    int e  = blockIdx.x >> 7;            // 8 experts x 128 blocks
    int mt = blockIdx.x & 127;
    int cnt = counts[e];
    int padded = (cnt + 127) & ~127;
    int m0 = mt * 32;
    if (m0 >= padded) return;
    int base = poff[e];
#pragma unroll 4
    for (int it = 0; it < 32; ++it) {
        int idx = it * 256 + threadIdx.x;    // 32 rows x 256 float4
        int r  = idx >> 8;
        int c4 = idx & 255;
        int m  = m0 + r;
        int mc = (m < cnt) ? m : cnt - 1;
        int t  = tok_list[e * T_TOK + mc];
        float4 v = *(const float4*)(x + (size_t)t * H_DIM + c4 * 4);
        u16x4 o;
        o[0] = f2bf(v.x); o[1] = f2bf(v.y); o[2] = f2bf(v.z); o[3] = f2bf(v.w);
        *(u16x4*)(xg + (size_t)(base + m) * H_DIM + c4 * 4) = o;
    }
}

// ---------------- Transpose+convert: [K][N] fp32 -> [N][K] bf16 ----------------
// 64x64 tile per block; float4 global reads, 16 B (8x bf16) global stores.
__global__ __launch_bounds__(256) void transpose_cvt(
    const float* __restrict__ in, unsigned short* __restrict__ out, int K, int N)
{
    int e = blockIdx.z;
    in  += (size_t)e * K * N;
    out += (size_t)e * K * N;
    int k0 = blockIdx.y * 64, n0 = blockIdx.x * 64;
    __shared__ float t[64][65];
#pragma unroll
    for (int it = 0; it < 4; ++it) {
        int idx = it * 256 + threadIdx.x;    // 1024 float4 slots
        int r = idx >> 4, c4 = idx & 15;
        float4 v = *(const float4*)(in + (size_t)(k0 + r) * N + n0 + c4 * 4);
        t[r][c4 * 4 + 0] = v.x; t[r][c4 * 4 + 1] = v.y;
        t[r][c4 * 4 + 2] = v.z; t[r][c4 * 4 + 3] = v.w;
    }
    __syncthreads();
#pragma unroll
    for (int it = 0; it < 2; ++it) {
        int slot = it * 256 + threadIdx.x;   // 64 n-rows x 8 k-groups
        int n = slot >> 3, kg = slot & 7;
        u16x8 o;
#pragma unroll
        for (int j = 0; j < 8; ++j) o[j] = f2bf(t[kg * 8 + j][n]);
        *(u16x8*)(out + (size_t)(n0 + n) * K + k0 + kg * 8) = o;
    }
}

// ---------------- MLP1: h = silu(X Wg) * (X Wu), MFMA grouped ----------------
__global__ __launch_bounds__(256, 2) void mlp1_kernel(
    const unsigned short* __restrict__ xg,
    const unsigned short* __restrict__ wgT, const unsigned short* __restrict__ wuT,
    const int* __restrict__ counts, const int* __restrict__ poff,
    unsigned short* __restrict__ hbuf)
{
    int e = blockIdx.z;
    int cnt = counts[e];
    int m0 = blockIdx.y * 128;
    if (m0 >= cnt) return;
    int n0 = blockIdx.x * 128;

    const unsigned short* A  = xg  + (size_t)(poff[e] + m0) * H_DIM;
    const unsigned short* Bg = wgT + (size_t)e * I_DIM * H_DIM + (size_t)n0 * H_DIM;
    const unsigned short* Bu = wuT + (size_t)e * I_DIM * H_DIM + (size_t)n0 * H_DIM;

    __shared__ char sm[49152];
    char* sA  = sm;
    char* sBg = sm + 16384;
    char* sBu = sm + 32768;

    int tid = threadIdx.x, lane = tid & 63, wv = tid >> 6;
    int wm = (wv >> 1) * 64, wn = (wv & 1) * 64;
    int q = lane >> 4, rl = lane & 15;

    f32x4 accg[4][4], accu[4][4];
#pragma unroll
    for (int i = 0; i < 4; ++i)
#pragma unroll
        for (int j = 0; j < 4; ++j) { accg[i][j] = (f32x4){0.f,0.f,0.f,0.f}; accu[i][j] = (f32x4){0.f,0.f,0.f,0.f}; }

    for (int k0 = 0; k0 < H_DIM; k0 += 64) {
        stage_tile64(A,  H_DIM, k0, sA,  tid, wv);
        stage_tile64(Bg, H_DIM, k0, sBg, tid, wv);
        stage_tile64(Bu, H_DIM, k0, sBu, tid, wv);
        __syncthreads();

#pragma unroll
        for (int h = 0; h < 2; ++h) {
            bf16x8 af[4], bgf[4], bu2[4];
#pragma unroll
            for (int i = 0; i < 4; ++i) af[i]  = frag_ld64(sA,  wm + i * 16 + rl, h * 4 + q);
#pragma unroll
            for (int j = 0; j < 4; ++j) { bgf[j] = frag_ld64(sBg, wn + j * 16 + rl, h * 4 + q);
                                          bu2[j] = frag_ld64(sBu, wn + j * 16 + rl, h * 4 + q); }
#pragma unroll
            for (int i = 0; i < 4; ++i)
#pragma unroll
                for (int j = 0; j < 4; ++j) {
                    accg[i][j] = __builtin_amdgcn_mfma_f32_16x16x32_bf16(af[i], bgf[j], accg[i][j], 0, 0, 0);
                    accu[i][j] = __builtin_amdgcn_mfma_f32_16x16x32_bf16(af[i], bu2[j], accu[i][j], 0, 0, 0);
                }
        }
        __syncthreads();
    }

    size_t hrow0 = (size_t)(poff[e] + m0);
#pragma unroll
    for (int i = 0; i < 4; ++i)
#pragma unroll
        for (int p = 0; p < 4; ++p) {
            int row = wm + i * 16 + q * 4 + p;
            unsigned short* orow = hbuf + (hrow0 + row) * I_DIM + n0 + wn + rl;
#pragma unroll
            for (int j = 0; j < 4; ++j) {
                float g = accg[i][j][p], u = accu[i][j][p];
                float hv = g / (1.f + __expf(-g)) * u;
                orow[j * 16] = f2bf(hv);
            }
        }
}

// ---------------- MLP2: y = h Wd (unweighted partials, plain stores) ----------------
__global__ __launch_bounds__(256, 2) void mlp2_kernel(
    const unsigned short* __restrict__ hbuf,
    const unsigned short* __restrict__ wdT,
    const int* __restrict__ counts, const int* __restrict__ poff,
    float* __restrict__ ybuf)
{
    int e = blockIdx.z;
    int cnt = counts[e];
    int m0 = blockIdx.y * 128;
    if (m0 >= cnt) return;
    int n0 = blockIdx.x * 128;

    const unsigned short* A = hbuf + (size_t)(poff[e] + m0) * I_DIM;
    const unsigned short* B = wdT  + (size_t)e * H_DIM * I_DIM + (size_t)n0 * I_DIM;

    __shared__ char sm[32768];
    char* sA = sm;
    char* sB = sm + 16384;

    int tid = threadIdx.x, lane = tid & 63, wv = tid >> 6;
    int wm = (wv >> 1) * 64, wn = (wv & 1) * 64;
    int q = lane >> 4, rl = lane & 15;

    f32x4 acc[4][4];
#pragma unroll
    for (int i = 0; i < 4; ++i)
#pragma unroll
        for (int j = 0; j < 4; ++j) acc[i][j] = (f32x4){0.f,0.f,0.f,0.f};

    for (int k0 = 0; k0 < I_DIM; k0 += 64) {
        stage_tile64(A, I_DIM, k0, sA, tid, wv);
        stage_tile64(B, I_DIM, k0, sB, tid, wv);
        __syncthreads();

#pragma unroll
        for (int h = 0; h < 2; ++h) {
            bf16x8 af[4], bf[4];
#pragma unroll
            for (int i = 0; i < 4; ++i) af[i] = frag_ld64(sA, wm + i * 16 + rl, h * 4 + q);
#pragma unroll
            for (int j = 0; j < 4; ++j) bf[j] = frag_ld64(sB, wn + j * 16 + rl, h * 4 + q);
#pragma unroll
            for (int i = 0; i < 4; ++i)
#pragma unroll
                for (int j = 0; j < 4; ++j)
                    acc[i][j] = __builtin_amdgcn_mfma_f32_16x16x32_bf16(af[i], bf[j], acc[i][j], 0, 0, 0);
        }
        __syncthreads();
    }

    size_t yrow0 = (size_t)(poff[e] + m0);
#pragma unroll
    for (int i = 0; i < 4; ++i)
#pragma unroll
        for (int p = 0; p < 4; ++p) {
            int row = wm + i * 16 + q * 4 + p;
            float* op = ybuf + (yrow0 + row) * H_DIM + n0 + wn + rl;
#pragma unroll
            for (int j = 0; j < 4; ++j) op[j * 16] = acc[i][j][p];
        }
}

// ---------------- Combine: out[t] = w0*y[slot0] + w1*y[slot1] ----------------
// One block per token; fully coalesced float4.
__global__ __launch_bounds__(256) void combine_kernel(
    const float* __restrict__ ybuf, const int* __restrict__ poff,
    const int* __restrict__ tslot, const float* __restrict__ w_list,
    float* __restrict__ out)
{
    int t  = blockIdx.x;
    int c4 = threadIdx.x;                      // 256 float4 = 1024 floats = H
    int s0 = tslot[t * 2 + 0], s1 = tslot[t * 2 + 1];
    float w0 = w_list[s0], w1 = w_list[s1];
    int e0 = s0 >> 12, p0 = s0 & 4095;         // T_TOK = 4096
    int e1 = s1 >> 12, p1 = s1 & 4095;
    size_t r0 = (size_t)(poff[e0] + p0) * H_DIM;
    size_t r1 = (size_t)(poff[e1] + p1) * H_DIM;
    float4 a = *(const float4*)(ybuf + r0 + c4 * 4);
    float4 b = *(const float4*)(ybuf + r1 + c4 * 4);
    float4 o;
    o.x = w0 * a.x + w1 * b.x;
    o.y = w0 * a.y + w1 * b.y;
    o.z = w0 * a.z + w1 * b.z;
    o.w = w0 * a.w + w1 * b.w;
    *(float4*)(out + (size_t)t * H_DIM + c4 * 4) = o;
}

extern "C" void kernel_launch(void* const* d_in, const int* in_sizes, int n_in,
                              void* d_out, int out_size, void* d_ws, size_t ws_size,
                              hipStream_t stream)
{
    const float* x      = (const float*)d_in[0];   // [T,H]
    const float* gate_w = (const float*)d_in[1];   // [E,H]
    const float* w_gate = (const float*)d_in[2];   // [E,H,I]
    const float* w_up   = (const float*)d_in[3];   // [E,H,I]
    const float* w_down = (const float*)d_in[4];   // [E,I,H]

    float* out        = (float*)d_out;                 // [T,H]
    float* logits_out = out + (size_t)T_TOK * H_DIM;   // [T,E]

    // Workspace layout
    char* ws = (char*)d_ws;
    int*   counts   = (int*)ws;                        // 8 ints
    int*   poff     = (int*)(ws + 64);                 // 8 ints (padded offsets)
    int*   tok_list = (int*)(ws + 1024);               // E*T ints (128 KB)
    float* w_list   = (float*)(ws + 1024 + E_NUM * T_TOK * 4);          // 128 KB
    int*   tslot    = (int*)(ws + 1024 + 2 * E_NUM * T_TOK * 4);        // 2*T ints (32 KB)

    const size_t XG_ROWS = 9216;                       // 8192 + 8*128 padding
    const size_t OFF_XG = 1u << 20;
    const size_t OFF_HB = OFF_XG + XG_ROWS * H_DIM * 2;                 // xg: 18.9 MB
    const size_t OFF_WG = OFF_HB + XG_ROWS * I_DIM * 2;                 // hbuf: 37.7 MB
    const size_t OFF_WU = OFF_WG + (size_t)E_NUM * H_DIM * I_DIM * 2;   // 33.6 MB each
    const size_t OFF_WD = OFF_WU + (size_t)E_NUM * H_DIM * I_DIM * 2;

    unsigned short* xg   = (unsigned short*)(ws + OFF_XG);
    unsigned short* hbuf = (unsigned short*)(ws + OFF_HB);
    unsigned short* wgT  = (unsigned short*)(ws + OFF_WG);  // [E][I][H]
    unsigned short* wuT  = (unsigned short*)(ws + OFF_WU);  // [E][I][H]
    unsigned short* wdT  = (unsigned short*)(ws + OFF_WD);  // [E][H][I]
    // ybuf (f32 partials, 37.7 MB) ALIASES wgT/wuT — those are dead after mlp1,
    // and mlp2 (which writes ybuf) is stream-ordered after mlp1.
    float* ybuf = (float*)(ws + OFF_WG);

    hipMemsetAsync(counts, 0, E_NUM * sizeof(int), stream);

    router_kernel<<<T_TOK / 4, 256, 0, stream>>>(x, gate_w, logits_out, counts, tok_list, w_list, tslot);
    offsets_kernel<<<1, 64, 0, stream>>>(counts, poff);

    dim3 gt1(I_DIM / 64, H_DIM / 64, E_NUM);
    transpose_cvt<<<gt1, 256, 0, stream>>>(w_gate, wgT, H_DIM, I_DIM);
    transpose_cvt<<<gt1, 256, 0, stream>>>(w_up,   wuT, H_DIM, I_DIM);
    dim3 gt2(H_DIM / 64, I_DIM / 64, E_NUM);
    transpose_cvt<<<gt2, 256, 0, stream>>>(w_down, wdT, I_DIM, H_DIM);

    gather_x<<<E_NUM * 128, 256, 0, stream>>>(x, counts, poff, tok_list, xg);

    dim3 g1(I_DIM / 128, T_TOK / 128, E_NUM);
    mlp1_kernel<<<g1, 256, 0, stream>>>(xg, wgT, wuT, counts, poff, hbuf);

    dim3 g2(H_DIM / 128, T_TOK / 128, E_NUM);
    mlp2_kernel<<<g2, 256, 0, stream>>>(hbuf, wdT, counts, poff, ybuf);

    combine_kernel<<<T_TOK, 256, 0, stream>>>(ybuf, poff, tslot, w_list, out);
}

// Round 5
// 417.186 us; speedup vs baseline: 1.3354x; 1.2028x over previous
//
#include <hip/hip_runtime.h>
#include <hip/hip_bf16.h>
#include <math.h>

// Problem constants (B=2,S=2048 -> T=4096, H=1024, I=2048, E=8, top-2)
#define T_TOK 4096
#define H_DIM 1024
#define I_DIM 2048
#define E_NUM 8

typedef __bf16 bf16x8 __attribute__((ext_vector_type(8)));
typedef float  f32x4  __attribute__((ext_vector_type(4)));
typedef unsigned short u16x4 __attribute__((ext_vector_type(4)));
typedef unsigned short u16x8 __attribute__((ext_vector_type(8)));

// ---- helpers -------------------------------------------------------------
__device__ inline void gll16(const void* g, void* l) {
    __builtin_amdgcn_global_load_lds(
        (const __attribute__((address_space(1))) void*)g,
        (__attribute__((address_space(3))) void*)l, 16, 0, 0);
}

__device__ inline unsigned short f2bf(float f) {
    union { float f; unsigned u; } v; v.f = f;
    unsigned r = v.u + 0x7FFF + ((v.u >> 16) & 1);   // RNE
    return (unsigned short)(r >> 16);
}

// Stage a 128-row x 64-col bf16 tile (16 KB) into LDS via global_load_lds.
// Physical LDS layout: row-major, 128 B/row; physical k-group g holds logical
// k-group g ^ (row & 7)  (XOR swizzle -> spread banks on frag reads).
__device__ inline void stage_tile64(const unsigned short* gbase, size_t stride_elems,
                                    int k0, char* smbase, int tid, int wv) {
#pragma unroll
    for (int it = 0; it < 4; ++it) {
        int idx = it * 256 + tid;            // 0..1023, 16 B each
        int r   = idx >> 3;                  // tile row 0..127
        int kg  = (idx & 7) ^ (r & 7);       // logical k-group for this slot
        const void* g = gbase + (size_t)r * stride_elems + k0 + kg * 8;
        void* l = smbase + it * 4096 + wv * 1024;   // wave-uniform base
        gll16(g, l);
    }
}

__device__ inline bf16x8 frag_ld64(const char* smbase, int row, int kg_log) {
    int kg = kg_log ^ (row & 7);
    return *(const bf16x8*)(smbase + row * 128 + kg * 16);
}

// ---------------- Router: per-token top-2, NO atomics ----------------
__global__ __launch_bounds__(256) void router_kernel(
    const float* __restrict__ x, const float* __restrict__ gw,
    float* __restrict__ logits_out, int* __restrict__ te, float2* __restrict__ tw)
{
    int wave = threadIdx.x >> 6;
    int lane = threadIdx.x & 63;
    int t = blockIdx.x * 4 + wave;
    if (t >= T_TOK) return;

    float xs[16];
#pragma unroll
    for (int i = 0; i < 16; ++i) xs[i] = x[(size_t)t * H_DIM + i * 64 + lane];

    float lg[E_NUM];
#pragma unroll
    for (int e = 0; e < E_NUM; ++e) {
        float acc = 0.f;
#pragma unroll
        for (int i = 0; i < 16; ++i) acc += xs[i] * gw[e * H_DIM + i * 64 + lane];
#pragma unroll
        for (int off = 32; off >= 1; off >>= 1) acc += __shfl_xor(acc, off, 64);
        lg[e] = acc;
    }

    if (lane == 0) {
#pragma unroll
        for (int e = 0; e < E_NUM; ++e) logits_out[(size_t)t * E_NUM + e] = lg[e];
        float m = lg[0];
        for (int e = 1; e < E_NUM; ++e) m = fmaxf(m, lg[e]);
        float p[E_NUM]; float s = 0.f;
        for (int e = 0; e < E_NUM; ++e) { p[e] = expf(lg[e] - m); s += p[e]; }
        float invs = 1.f / s;
        for (int e = 0; e < E_NUM; ++e) p[e] *= invs;
        int i0 = 0; float p0 = p[0];
        for (int e = 1; e < E_NUM; ++e) if (p[e] > p0) { p0 = p[e]; i0 = e; }
        int i1 = -1; float p1 = -1.f;
        for (int e = 0; e < E_NUM; ++e) { if (e == i0) continue; if (p[e] > p1) { p1 = p[e]; i1 = e; } }
        float inv = 1.f / (p0 + p1);
        te[t] = i0 | (i1 << 4);
        tw[t] = make_float2(p0 * inv, p1 * inv);
    }
}

// ---------------- Compaction scan: 1 block per expert, ballot prefix ----------------
__global__ __launch_bounds__(256) void scan_kernel(
    const int* __restrict__ te, const float2* __restrict__ tw,
    int* __restrict__ counts, int* __restrict__ tok_list,
    float* __restrict__ w_list, int* __restrict__ tslot)
{
    int e = blockIdx.x;                          // 0..7
    int tid = threadIdx.x, lane = tid & 63, wv = tid >> 6;

    int    pk[16];
    float2 w2[16];
#pragma unroll
    for (int c = 0; c < 16; ++c) pk[c] = te[c * 256 + tid];
#pragma unroll
    for (int c = 0; c < 16; ++c) w2[c] = tw[c * 256 + tid];

    __shared__ int wbase[4];
    int running = 0;
#pragma unroll
    for (int c = 0; c < 16; ++c) {
        int t  = c * 256 + tid;
        int e0 = pk[c] & 15, e1 = pk[c] >> 4;
        bool f0 = (e0 == e), f1 = (e1 == e);
        bool f  = f0 || f1;
        unsigned long long b = __ballot(f);
        int pre = __popcll(b & ((1ull << lane) - 1ull));
        if (lane == 0) wbase[wv] = __popcll(b);
        __syncthreads();
        int base = running;
#pragma unroll
        for (int w = 0; w < 4; ++w) if (w < wv) base += wbase[w];
        int tot = wbase[0] + wbase[1] + wbase[2] + wbase[3];
        if (f) {
            int pos = base + pre;
            tok_list[e * T_TOK + pos] = t;
            w_list[e * T_TOK + pos]   = f0 ? w2[c].x : w2[c].y;
            tslot[t * 2 + (f0 ? 0 : 1)] = e * T_TOK + pos;
        }
        running += tot;
        __syncthreads();                         // protect wbase for next chunk
    }
    if (tid == 0) counts[e] = running;
}

// ---------------- Padded offsets (128-aligned per expert) ----------------
__global__ void offsets_kernel(const int* __restrict__ counts, int* __restrict__ poff)
{
    if (threadIdx.x == 0 && blockIdx.x == 0) {
        int s = 0;
        for (int e = 0; e < E_NUM; ++e) { poff[e] = s; s += ((counts[e] + 127) >> 7) << 7; }
    }
}

// ---------------- Gather x rows -> xg (bf16, padded slots) ----------------
__global__ __launch_bounds__(256) void gather_x(
    const float* __restrict__ x, const int* __restrict__ counts,
    const int* __restrict__ poff, const int* __restrict__ tok_list,
    unsigned short* __restrict__ xg)
{
    int e  = blockIdx.x >> 7;            // 8 experts x 128 blocks
    int mt = blockIdx.x & 127;
    int cnt = counts[e];
    int padded = (cnt + 127) & ~127;
    int m0 = mt * 32;
    if (m0 >= padded) return;
    int base = poff[e];
#pragma unroll 4
    for (int it = 0; it < 32; ++it) {
        int idx = it * 256 + threadIdx.x;    // 32 rows x 256 float4
        int r  = idx >> 8;
        int c4 = idx & 255;
        int m  = m0 + r;
        int mc = (m < cnt) ? m : cnt - 1;
        int t  = tok_list[e * T_TOK + mc];
        float4 v = *(const float4*)(x + (size_t)t * H_DIM + c4 * 4);
        u16x4 o;
        o[0] = f2bf(v.x); o[1] = f2bf(v.y); o[2] = f2bf(v.z); o[3] = f2bf(v.w);
        *(u16x4*)(xg + (size_t)(base + m) * H_DIM + c4 * 4) = o;
    }
}

// ---------------- Transpose+convert: [K][N] fp32 -> [N][K] bf16 ----------------
// 64x64 tile per block; float4 global reads, 16 B (8x bf16) global stores.
__global__ __launch_bounds__(256) void transpose_cvt(
    const float* __restrict__ in, unsigned short* __restrict__ out, int K, int N)
{
    int e = blockIdx.z;
    in  += (size_t)e * K * N;
    out += (size_t)e * K * N;
    int k0 = blockIdx.y * 64, n0 = blockIdx.x * 64;
    __shared__ float t[64][65];
#pragma unroll
    for (int it = 0; it < 4; ++it) {
        int idx = it * 256 + threadIdx.x;    // 1024 float4 slots
        int r = idx >> 4, c4 = idx & 15;
        float4 v = *(const float4*)(in + (size_t)(k0 + r) * N + n0 + c4 * 4);
        t[r][c4 * 4 + 0] = v.x; t[r][c4 * 4 + 1] = v.y;
        t[r][c4 * 4 + 2] = v.z; t[r][c4 * 4 + 3] = v.w;
    }
    __syncthreads();
#pragma unroll
    for (int it = 0; it < 2; ++it) {
        int slot = it * 256 + threadIdx.x;   // 64 n-rows x 8 k-groups
        int n = slot >> 3, kg = slot & 7;
        u16x8 o;
#pragma unroll
        for (int j = 0; j < 8; ++j) o[j] = f2bf(t[kg * 8 + j][n]);
        *(u16x8*)(out + (size_t)(n0 + n) * K + k0 + kg * 8) = o;
    }
}

// ---------------- MLP1: h = silu(X Wg) * (X Wu), MFMA grouped ----------------
__global__ __launch_bounds__(256, 2) void mlp1_kernel(
    const unsigned short* __restrict__ xg,
    const unsigned short* __restrict__ wgT, const unsigned short* __restrict__ wuT,
    const int* __restrict__ counts, const int* __restrict__ poff,
    unsigned short* __restrict__ hbuf)
{
    int e = blockIdx.z;
    int cnt = counts[e];
    int m0 = blockIdx.y * 128;
    if (m0 >= cnt) return;
    int n0 = blockIdx.x * 128;

    const unsigned short* A  = xg  + (size_t)(poff[e] + m0) * H_DIM;
    const unsigned short* Bg = wgT + (size_t)e * I_DIM * H_DIM + (size_t)n0 * H_DIM;
    const unsigned short* Bu = wuT + (size_t)e * I_DIM * H_DIM + (size_t)n0 * H_DIM;

    __shared__ char sm[49152];
    char* sA  = sm;
    char* sBg = sm + 16384;
    char* sBu = sm + 32768;

    int tid = threadIdx.x, lane = tid & 63, wv = tid >> 6;
    int wm = (wv >> 1) * 64, wn = (wv & 1) * 64;
    int q = lane >> 4, rl = lane & 15;

    f32x4 accg[4][4], accu[4][4];
#pragma unroll
    for (int i = 0; i < 4; ++i)
#pragma unroll
        for (int j = 0; j < 4; ++j) { accg[i][j] = (f32x4){0.f,0.f,0.f,0.f}; accu[i][j] = (f32x4){0.f,0.f,0.f,0.f}; }

    for (int k0 = 0; k0 < H_DIM; k0 += 64) {
        stage_tile64(A,  H_DIM, k0, sA,  tid, wv);
        stage_tile64(Bg, H_DIM, k0, sBg, tid, wv);
        stage_tile64(Bu, H_DIM, k0, sBu, tid, wv);
        __syncthreads();

#pragma unroll
        for (int h = 0; h < 2; ++h) {
            bf16x8 af[4], bgf[4], bu2[4];
#pragma unroll
            for (int i = 0; i < 4; ++i) af[i]  = frag_ld64(sA,  wm + i * 16 + rl, h * 4 + q);
#pragma unroll
            for (int j = 0; j < 4; ++j) { bgf[j] = frag_ld64(sBg, wn + j * 16 + rl, h * 4 + q);
                                          bu2[j] = frag_ld64(sBu, wn + j * 16 + rl, h * 4 + q); }
#pragma unroll
            for (int i = 0; i < 4; ++i)
#pragma unroll
                for (int j = 0; j < 4; ++j) {
                    accg[i][j] = __builtin_amdgcn_mfma_f32_16x16x32_bf16(af[i], bgf[j], accg[i][j], 0, 0, 0);
                    accu[i][j] = __builtin_amdgcn_mfma_f32_16x16x32_bf16(af[i], bu2[j], accu[i][j], 0, 0, 0);
                }
        }
        __syncthreads();
    }

    size_t hrow0 = (size_t)(poff[e] + m0);
#pragma unroll
    for (int i = 0; i < 4; ++i)
#pragma unroll
        for (int p = 0; p < 4; ++p) {
            int row = wm + i * 16 + q * 4 + p;
            unsigned short* orow = hbuf + (hrow0 + row) * I_DIM + n0 + wn + rl;
#pragma unroll
            for (int j = 0; j < 4; ++j) {
                float g = accg[i][j][p], u = accu[i][j][p];
                float hv = g / (1.f + __expf(-g)) * u;
                orow[j * 16] = f2bf(hv);
            }
        }
}

// ---------------- MLP2: y = h Wd (unweighted partials, plain stores) ----------------
__global__ __launch_bounds__(256, 2) void mlp2_kernel(
    const unsigned short* __restrict__ hbuf,
    const unsigned short* __restrict__ wdT,
    const int* __restrict__ counts, const int* __restrict__ poff,
    float* __restrict__ ybuf)
{
    int e = blockIdx.z;
    int cnt = counts[e];
    int m0 = blockIdx.y * 128;
    if (m0 >= cnt) return;
    int n0 = blockIdx.x * 128;

    const unsigned short* A = hbuf + (size_t)(poff[e] + m0) * I_DIM;
    const unsigned short* B = wdT  + (size_t)e * H_DIM * I_DIM + (size_t)n0 * I_DIM;

    __shared__ char sm[32768];
    char* sA = sm;
    char* sB = sm + 16384;

    int tid = threadIdx.x, lane = tid & 63, wv = tid >> 6;
    int wm = (wv >> 1) * 64, wn = (wv & 1) * 64;
    int q = lane >> 4, rl = lane & 15;

    f32x4 acc[4][4];
#pragma unroll
    for (int i = 0; i < 4; ++i)
#pragma unroll
        for (int j = 0; j < 4; ++j) acc[i][j] = (f32x4){0.f,0.f,0.f,0.f};

    for (int k0 = 0; k0 < I_DIM; k0 += 64) {
        stage_tile64(A, I_DIM, k0, sA, tid, wv);
        stage_tile64(B, I_DIM, k0, sB, tid, wv);
        __syncthreads();

#pragma unroll
        for (int h = 0; h < 2; ++h) {
            bf16x8 af[4], bf[4];
#pragma unroll
            for (int i = 0; i < 4; ++i) af[i] = frag_ld64(sA, wm + i * 16 + rl, h * 4 + q);
#pragma unroll
            for (int j = 0; j < 4; ++j) bf[j] = frag_ld64(sB, wn + j * 16 + rl, h * 4 + q);
#pragma unroll
            for (int i = 0; i < 4; ++i)
#pragma unroll
                for (int j = 0; j < 4; ++j)
                    acc[i][j] = __builtin_amdgcn_mfma_f32_16x16x32_bf16(af[i], bf[j], acc[i][j], 0, 0, 0);
        }
        __syncthreads();
    }

    size_t yrow0 = (size_t)(poff[e] + m0);
#pragma unroll
    for (int i = 0; i < 4; ++i)
#pragma unroll
        for (int p = 0; p < 4; ++p) {
            int row = wm + i * 16 + q * 4 + p;
            float* op = ybuf + (yrow0 + row) * H_DIM + n0 + wn + rl;
#pragma unroll
            for (int j = 0; j < 4; ++j) op[j * 16] = acc[i][j][p];
        }
}

// ---------------- Combine: out[t] = w0*y[slot0] + w1*y[slot1] ----------------
// One block per token; fully coalesced float4.
__global__ __launch_bounds__(256) void combine_kernel(
    const float* __restrict__ ybuf, const int* __restrict__ poff,
    const int* __restrict__ tslot, const float* __restrict__ w_list,
    float* __restrict__ out)
{
    int t  = blockIdx.x;
    int c4 = threadIdx.x;                      // 256 float4 = 1024 floats = H
    int s0 = tslot[t * 2 + 0], s1 = tslot[t * 2 + 1];
    float w0 = w_list[s0], w1 = w_list[s1];
    int e0 = s0 >> 12, p0 = s0 & 4095;         // T_TOK = 4096
    int e1 = s1 >> 12, p1 = s1 & 4095;
    size_t r0 = (size_t)(poff[e0] + p0) * H_DIM;
    size_t r1 = (size_t)(poff[e1] + p1) * H_DIM;
    float4 a = *(const float4*)(ybuf + r0 + c4 * 4);
    float4 b = *(const float4*)(ybuf + r1 + c4 * 4);
    float4 o;
    o.x = w0 * a.x + w1 * b.x;
    o.y = w0 * a.y + w1 * b.y;
    o.z = w0 * a.z + w1 * b.z;
    o.w = w0 * a.w + w1 * b.w;
    *(float4*)(out + (size_t)t * H_DIM + c4 * 4) = o;
}

extern "C" void kernel_launch(void* const* d_in, const int* in_sizes, int n_in,
                              void* d_out, int out_size, void* d_ws, size_t ws_size,
                              hipStream_t stream)
{
    const float* x      = (const float*)d_in[0];   // [T,H]
    const float* gate_w = (const float*)d_in[1];   // [E,H]
    const float* w_gate = (const float*)d_in[2];   // [E,H,I]
    const float* w_up   = (const float*)d_in[3];   // [E,H,I]
    const float* w_down = (const float*)d_in[4];   // [E,I,H]

    float* out        = (float*)d_out;                 // [T,H]
    float* logits_out = out + (size_t)T_TOK * H_DIM;   // [T,E]

    // Workspace layout
    char* ws = (char*)d_ws;
    int*   counts   = (int*)ws;                        // 8 ints
    int*   poff     = (int*)(ws + 64);                 // 8 ints (padded offsets)
    int*   tok_list = (int*)(ws + 1024);               // E*T ints (128 KB)
    float* w_list   = (float*)(ws + 1024 + E_NUM * T_TOK * 4);          // 128 KB
    int*   tslot    = (int*)(ws + 1024 + 2 * E_NUM * T_TOK * 4);        // 2*T ints (32 KB)
    int*   te       = (int*)(ws + 1024 + 2 * E_NUM * T_TOK * 4 + 2 * T_TOK * 4);   // T ints
    float2* tw      = (float2*)(ws + 1024 + 2 * E_NUM * T_TOK * 4 + 3 * T_TOK * 4); // T float2

    const size_t XG_ROWS = 9216;                       // 8192 + 8*128 padding
    const size_t OFF_XG = 1u << 20;
    const size_t OFF_HB = OFF_XG + XG_ROWS * H_DIM * 2;                 // xg: 18.9 MB
    const size_t OFF_WG = OFF_HB + XG_ROWS * I_DIM * 2;                 // hbuf: 37.7 MB
    const size_t OFF_WU = OFF_WG + (size_t)E_NUM * H_DIM * I_DIM * 2;   // 33.6 MB each
    const size_t OFF_WD = OFF_WU + (size_t)E_NUM * H_DIM * I_DIM * 2;

    unsigned short* xg   = (unsigned short*)(ws + OFF_XG);
    unsigned short* hbuf = (unsigned short*)(ws + OFF_HB);
    unsigned short* wgT  = (unsigned short*)(ws + OFF_WG);  // [E][I][H]
    unsigned short* wuT  = (unsigned short*)(ws + OFF_WU);  // [E][I][H]
    unsigned short* wdT  = (unsigned short*)(ws + OFF_WD);  // [E][H][I]
    // ybuf (f32 partials, 37.7 MB) ALIASES wgT/wuT — those are dead after mlp1,
    // and mlp2 (which writes ybuf) is stream-ordered after mlp1.
    float* ybuf = (float*)(ws + OFF_WG);

    router_kernel<<<T_TOK / 4, 256, 0, stream>>>(x, gate_w, logits_out, te, tw);
    scan_kernel<<<E_NUM, 256, 0, stream>>>(te, tw, counts, tok_list, w_list, tslot);
    offsets_kernel<<<1, 64, 0, stream>>>(counts, poff);

    dim3 gt1(I_DIM / 64, H_DIM / 64, E_NUM);
    transpose_cvt<<<gt1, 256, 0, stream>>>(w_gate, wgT, H_DIM, I_DIM);
    transpose_cvt<<<gt1, 256, 0, stream>>>(w_up,   wuT, H_DIM, I_DIM);
    dim3 gt2(H_DIM / 64, I_DIM / 64, E_NUM);
    transpose_cvt<<<gt2, 256, 0, stream>>>(w_down, wdT, I_DIM, H_DIM);

    gather_x<<<E_NUM * 128, 256, 0, stream>>>(x, counts, poff, tok_list, xg);

    dim3 g1(I_DIM / 128, T_TOK / 128, E_NUM);
    mlp1_kernel<<<g1, 256, 0, stream>>>(xg, wgT, wuT, counts, poff, hbuf);

    dim3 g2(H_DIM / 128, T_TOK / 128, E_NUM);
    mlp2_kernel<<<g2, 256, 0, stream>>>(hbuf, wdT, counts, poff, ybuf);

    combine_kernel<<<T_TOK, 256, 0, stream>>>(ybuf, poff, tslot, w_list, out);
}

// Round 6
// 414.281 us; speedup vs baseline: 1.3448x; 1.0070x over previous
//
#include <hip/hip_runtime.h>
#include <hip/hip_bf16.h>
#include <math.h>

// Problem constants (B=2,S=2048 -> T=4096, H=1024, I=2048, E=8, top-2)
#define T_TOK 4096
#define H_DIM 1024
#define I_DIM 2048
#define E_NUM 8

typedef __bf16 bf16x8 __attribute__((ext_vector_type(8)));
typedef float  f32x4  __attribute__((ext_vector_type(4)));
typedef unsigned short u16x4 __attribute__((ext_vector_type(4)));
typedef unsigned short u16x8 __attribute__((ext_vector_type(8)));

// ---- helpers -------------------------------------------------------------
__device__ inline void gll16(const void* g, void* l) {
    __builtin_amdgcn_global_load_lds(
        (const __attribute__((address_space(1))) void*)g,
        (__attribute__((address_space(3))) void*)l, 16, 0, 0);
}

__device__ inline unsigned short f2bf(float f) {
    union { float f; unsigned u; } v; v.f = f;
    unsigned r = v.u + 0x7FFF + ((v.u >> 16) & 1);   // RNE
    return (unsigned short)(r >> 16);
}

// Stage a 128-row x 64-col bf16 tile (16 KB) into LDS via global_load_lds.
// 512-thread version: 2 iterations x 512 slots x 16 B.
// Physical LDS layout: row-major, 128 B/row; physical k-group g holds logical
// k-group g ^ (row & 7)  (XOR swizzle -> spread banks on frag reads).
__device__ inline void stage_tile64_512(const unsigned short* gbase, size_t stride_elems,
                                        int k0, char* smbase, int tid, int wv) {
#pragma unroll
    for (int it = 0; it < 2; ++it) {
        int idx = it * 512 + tid;            // 0..1023, 16 B each
        int r   = idx >> 3;                  // tile row 0..127
        int kg  = (idx & 7) ^ (r & 7);       // logical k-group for this slot
        const void* g = gbase + (size_t)r * stride_elems + k0 + kg * 8;
        void* l = smbase + it * 8192 + wv * 1024;   // wave-uniform base
        gll16(g, l);
    }
}

__device__ inline bf16x8 frag_ld64(const char* smbase, int row, int kg_log) {
    int kg = kg_log ^ (row & 7);
    return *(const bf16x8*)(smbase + row * 128 + kg * 16);
}

// ---------------- Router: per-token top-2, NO atomics ----------------
__global__ __launch_bounds__(256) void router_kernel(
    const float* __restrict__ x, const float* __restrict__ gw,
    float* __restrict__ logits_out, int* __restrict__ te, float2* __restrict__ tw)
{
    int wave = threadIdx.x >> 6;
    int lane = threadIdx.x & 63;
    int t = blockIdx.x * 4 + wave;
    if (t >= T_TOK) return;

    float xs[16];
#pragma unroll
    for (int i = 0; i < 16; ++i) xs[i] = x[(size_t)t * H_DIM + i * 64 + lane];

    float lg[E_NUM];
#pragma unroll
    for (int e = 0; e < E_NUM; ++e) {
        float acc = 0.f;
#pragma unroll
        for (int i = 0; i < 16; ++i) acc += xs[i] * gw[e * H_DIM + i * 64 + lane];
#pragma unroll
        for (int off = 32; off >= 1; off >>= 1) acc += __shfl_xor(acc, off, 64);
        lg[e] = acc;
    }

    if (lane == 0) {
#pragma unroll
        for (int e = 0; e < E_NUM; ++e) logits_out[(size_t)t * E_NUM + e] = lg[e];
        float m = lg[0];
        for (int e = 1; e < E_NUM; ++e) m = fmaxf(m, lg[e]);
        float p[E_NUM]; float s = 0.f;
        for (int e = 0; e < E_NUM; ++e) { p[e] = expf(lg[e] - m); s += p[e]; }
        float invs = 1.f / s;
        for (int e = 0; e < E_NUM; ++e) p[e] *= invs;
        int i0 = 0; float p0 = p[0];
        for (int e = 1; e < E_NUM; ++e) if (p[e] > p0) { p0 = p[e]; i0 = e; }
        int i1 = -1; float p1 = -1.f;
        for (int e = 0; e < E_NUM; ++e) { if (e == i0) continue; if (p[e] > p1) { p1 = p[e]; i1 = e; } }
        float inv = 1.f / (p0 + p1);
        te[t] = i0 | (i1 << 4);
        tw[t] = make_float2(p0 * inv, p1 * inv);
    }
}

// ---------------- Compaction scan: 1 block per expert, ballot prefix ----------------
__global__ __launch_bounds__(256) void scan_kernel(
    const int* __restrict__ te, const float2* __restrict__ tw,
    int* __restrict__ counts, int* __restrict__ tok_list,
    float* __restrict__ w_list, int* __restrict__ tslot)
{
    int e = blockIdx.x;                          // 0..7
    int tid = threadIdx.x, lane = tid & 63, wv = tid >> 6;

    int    pk[16];
    float2 w2[16];
#pragma unroll
    for (int c = 0; c < 16; ++c) pk[c] = te[c * 256 + tid];
#pragma unroll
    for (int c = 0; c < 16; ++c) w2[c] = tw[c * 256 + tid];

    __shared__ int wbase[4];
    int running = 0;
#pragma unroll
    for (int c = 0; c < 16; ++c) {
        int t  = c * 256 + tid;
        int e0 = pk[c] & 15, e1 = pk[c] >> 4;
        bool f0 = (e0 == e), f1 = (e1 == e);
        bool f  = f0 || f1;
        unsigned long long b = __ballot(f);
        int pre = __popcll(b & ((1ull << lane) - 1ull));
        if (lane == 0) wbase[wv] = __popcll(b);
        __syncthreads();
        int base = running;
#pragma unroll
        for (int w = 0; w < 4; ++w) if (w < wv) base += wbase[w];
        int tot = wbase[0] + wbase[1] + wbase[2] + wbase[3];
        if (f) {
            int pos = base + pre;
            tok_list[e * T_TOK + pos] = t;
            w_list[e * T_TOK + pos]   = f0 ? w2[c].x : w2[c].y;
            tslot[t * 2 + (f0 ? 0 : 1)] = e * T_TOK + pos;
        }
        running += tot;
        __syncthreads();                         // protect wbase for next chunk
    }
    if (tid == 0) counts[e] = running;
}

// ---------------- Padded offsets (128-aligned per expert) ----------------
__global__ void offsets_kernel(const int* __restrict__ counts, int* __restrict__ poff)
{
    if (threadIdx.x == 0 && blockIdx.x == 0) {
        int s = 0;
        for (int e = 0; e < E_NUM; ++e) { poff[e] = s; s += ((counts[e] + 127) >> 7) << 7; }
    }
}

// ---------------- Gather x rows -> xg (bf16, padded slots) ----------------
__global__ __launch_bounds__(256) void gather_x(
    const float* __restrict__ x, const int* __restrict__ counts,
    const int* __restrict__ poff, const int* __restrict__ tok_list,
    unsigned short* __restrict__ xg)
{
    int e  = blockIdx.x >> 7;            // 8 experts x 128 blocks
    int mt = blockIdx.x & 127;
    int cnt = counts[e];
    int padded = (cnt + 127) & ~127;
    int m0 = mt * 32;
    if (m0 >= padded) return;
    int base = poff[e];
#pragma unroll 4
    for (int it = 0; it < 32; ++it) {
        int idx = it * 256 + threadIdx.x;    // 32 rows x 256 float4
        int r  = idx >> 8;
        int c4 = idx & 255;
        int m  = m0 + r;
        int mc = (m < cnt) ? m : cnt - 1;
        int t  = tok_list[e * T_TOK + mc];
        float4 v = *(const float4*)(x + (size_t)t * H_DIM + c4 * 4);
        u16x4 o;
        o[0] = f2bf(v.x); o[1] = f2bf(v.y); o[2] = f2bf(v.z); o[3] = f2bf(v.w);
        *(u16x4*)(xg + (size_t)(base + m) * H_DIM + c4 * 4) = o;
    }
}

// ---------------- Transpose+convert: [K][N] fp32 -> [N][K] bf16 ----------------
// 64x64 tile per block; float4 global reads, 16 B (8x bf16) global stores.
__global__ __launch_bounds__(256) void transpose_cvt(
    const float* __restrict__ in, unsigned short* __restrict__ out, int K, int N)
{
    int e = blockIdx.z;
    in  += (size_t)e * K * N;
    out += (size_t)e * K * N;
    int k0 = blockIdx.y * 64, n0 = blockIdx.x * 64;
    __shared__ float t[64][65];
#pragma unroll
    for (int it = 0; it < 4; ++it) {
        int idx = it * 256 + threadIdx.x;    // 1024 float4 slots
        int r = idx >> 4, c4 = idx & 15;
        float4 v = *(const float4*)(in + (size_t)(k0 + r) * N + n0 + c4 * 4);
        t[r][c4 * 4 + 0] = v.x; t[r][c4 * 4 + 1] = v.y;
        t[r][c4 * 4 + 2] = v.z; t[r][c4 * 4 + 3] = v.w;
    }
    __syncthreads();
#pragma unroll
    for (int it = 0; it < 2; ++it) {
        int slot = it * 256 + threadIdx.x;   // 64 n-rows x 8 k-groups
        int n = slot >> 3, kg = slot & 7;
        u16x8 o;
#pragma unroll
        for (int j = 0; j < 8; ++j) o[j] = f2bf(t[kg * 8 + j][n]);
        *(u16x8*)(out + (size_t)(n0 + n) * K + k0 + kg * 8) = o;
    }
}

// ---------------- MLP1: h = silu(X Wg) * (X Wu), MFMA grouped ----------------
// 512 threads / 8 waves; wave grid 4m x 2n, wave-tile 32x64 over 128x128.
__global__ __launch_bounds__(512, 4) void mlp1_kernel(
    const unsigned short* __restrict__ xg,
    const unsigned short* __restrict__ wgT, const unsigned short* __restrict__ wuT,
    const int* __restrict__ counts, const int* __restrict__ poff,
    unsigned short* __restrict__ hbuf)
{
    int e = blockIdx.z;
    int cnt = counts[e];
    int m0 = blockIdx.y * 128;
    if (m0 >= cnt) return;
    int n0 = blockIdx.x * 128;

    const unsigned short* A  = xg  + (size_t)(poff[e] + m0) * H_DIM;
    const unsigned short* Bg = wgT + (size_t)e * I_DIM * H_DIM + (size_t)n0 * H_DIM;
    const unsigned short* Bu = wuT + (size_t)e * I_DIM * H_DIM + (size_t)n0 * H_DIM;

    __shared__ char sm[49152];
    char* sA  = sm;
    char* sBg = sm + 16384;
    char* sBu = sm + 32768;

    int tid = threadIdx.x, lane = tid & 63, wv = tid >> 6;
    int wm = (wv >> 1) * 32, wn = (wv & 1) * 64;
    int q = lane >> 4, rl = lane & 15;

    f32x4 accg[2][4], accu[2][4];
#pragma unroll
    for (int i = 0; i < 2; ++i)
#pragma unroll
        for (int j = 0; j < 4; ++j) { accg[i][j] = (f32x4){0.f,0.f,0.f,0.f}; accu[i][j] = (f32x4){0.f,0.f,0.f,0.f}; }

    for (int k0 = 0; k0 < H_DIM; k0 += 64) {
        stage_tile64_512(A,  H_DIM, k0, sA,  tid, wv);
        stage_tile64_512(Bg, H_DIM, k0, sBg, tid, wv);
        stage_tile64_512(Bu, H_DIM, k0, sBu, tid, wv);
        __syncthreads();

#pragma unroll
        for (int h = 0; h < 2; ++h) {
            bf16x8 af[2], bgf[4], bu2[4];
#pragma unroll
            for (int i = 0; i < 2; ++i) af[i]  = frag_ld64(sA,  wm + i * 16 + rl, h * 4 + q);
#pragma unroll
            for (int j = 0; j < 4; ++j) { bgf[j] = frag_ld64(sBg, wn + j * 16 + rl, h * 4 + q);
                                          bu2[j] = frag_ld64(sBu, wn + j * 16 + rl, h * 4 + q); }
#pragma unroll
            for (int i = 0; i < 2; ++i)
#pragma unroll
                for (int j = 0; j < 4; ++j) {
                    accg[i][j] = __builtin_amdgcn_mfma_f32_16x16x32_bf16(af[i], bgf[j], accg[i][j], 0, 0, 0);
                    accu[i][j] = __builtin_amdgcn_mfma_f32_16x16x32_bf16(af[i], bu2[j], accu[i][j], 0, 0, 0);
                }
        }
        __syncthreads();
    }

    size_t hrow0 = (size_t)(poff[e] + m0);
#pragma unroll
    for (int i = 0; i < 2; ++i)
#pragma unroll
        for (int p = 0; p < 4; ++p) {
            int row = wm + i * 16 + q * 4 + p;
            unsigned short* orow = hbuf + (hrow0 + row) * I_DIM + n0 + wn + rl;
#pragma unroll
            for (int j = 0; j < 4; ++j) {
                float g = accg[i][j][p], u = accu[i][j][p];
                float hv = g / (1.f + __expf(-g)) * u;
                orow[j * 16] = f2bf(hv);
            }
        }
}

// ---------------- MLP2: y = h Wd (unweighted partials, plain stores) ----------------
// 512 threads / 8 waves; wave grid 4m x 2n, wave-tile 32x64 over 128x128.
__global__ __launch_bounds__(512, 4) void mlp2_kernel(
    const unsigned short* __restrict__ hbuf,
    const unsigned short* __restrict__ wdT,
    const int* __restrict__ counts, const int* __restrict__ poff,
    float* __restrict__ ybuf)
{
    int e = blockIdx.z;
    int cnt = counts[e];
    int m0 = blockIdx.y * 128;
    if (m0 >= cnt) return;
    int n0 = blockIdx.x * 128;

    const unsigned short* A = hbuf + (size_t)(poff[e] + m0) * I_DIM;
    const unsigned short* B = wdT  + (size_t)e * H_DIM * I_DIM + (size_t)n0 * I_DIM;

    __shared__ char sm[32768];
    char* sA = sm;
    char* sB = sm + 16384;

    int tid = threadIdx.x, lane = tid & 63, wv = tid >> 6;
    int wm = (wv >> 1) * 32, wn = (wv & 1) * 64;
    int q = lane >> 4, rl = lane & 15;

    f32x4 acc[2][4];
#pragma unroll
    for (int i = 0; i < 2; ++i)
#pragma unroll
        for (int j = 0; j < 4; ++j) acc[i][j] = (f32x4){0.f,0.f,0.f,0.f};

    for (int k0 = 0; k0 < I_DIM; k0 += 64) {
        stage_tile64_512(A, I_DIM, k0, sA, tid, wv);
        stage_tile64_512(B, I_DIM, k0, sB, tid, wv);
        __syncthreads();

#pragma unroll
        for (int h = 0; h < 2; ++h) {
            bf16x8 af[2], bf[4];
#pragma unroll
            for (int i = 0; i < 2; ++i) af[i] = frag_ld64(sA, wm + i * 16 + rl, h * 4 + q);
#pragma unroll
            for (int j = 0; j < 4; ++j) bf[j] = frag_ld64(sB, wn + j * 16 + rl, h * 4 + q);
#pragma unroll
            for (int i = 0; i < 2; ++i)
#pragma unroll
                for (int j = 0; j < 4; ++j)
                    acc[i][j] = __builtin_amdgcn_mfma_f32_16x16x32_bf16(af[i], bf[j], acc[i][j], 0, 0, 0);
        }
        __syncthreads();
    }

    size_t yrow0 = (size_t)(poff[e] + m0);
#pragma unroll
    for (int i = 0; i < 2; ++i)
#pragma unroll
        for (int p = 0; p < 4; ++p) {
            int row = wm + i * 16 + q * 4 + p;
            float* op = ybuf + (yrow0 + row) * H_DIM + n0 + wn + rl;
#pragma unroll
            for (int j = 0; j < 4; ++j) op[j * 16] = acc[i][j][p];
        }
}

// ---------------- Combine: out[t] = w0*y[slot0] + w1*y[slot1] ----------------
// One block per token; fully coalesced float4.
__global__ __launch_bounds__(256) void combine_kernel(
    const float* __restrict__ ybuf, const int* __restrict__ poff,
    const int* __restrict__ tslot, const float* __restrict__ w_list,
    float* __restrict__ out)
{
    int t  = blockIdx.x;
    int c4 = threadIdx.x;                      // 256 float4 = 1024 floats = H
    int s0 = tslot[t * 2 + 0], s1 = tslot[t * 2 + 1];
    float w0 = w_list[s0], w1 = w_list[s1];
    int e0 = s0 >> 12, p0 = s0 & 4095;         // T_TOK = 4096
    int e1 = s1 >> 12, p1 = s1 & 4095;
    size_t r0 = (size_t)(poff[e0] + p0) * H_DIM;
    size_t r1 = (size_t)(poff[e1] + p1) * H_DIM;
    float4 a = *(const float4*)(ybuf + r0 + c4 * 4);
    float4 b = *(const float4*)(ybuf + r1 + c4 * 4);
    float4 o;
    o.x = w0 * a.x + w1 * b.x;
    o.y = w0 * a.y + w1 * b.y;
    o.z = w0 * a.z + w1 * b.z;
    o.w = w0 * a.w + w1 * b.w;
    *(float4*)(out + (size_t)t * H_DIM + c4 * 4) = o;
}

extern "C" void kernel_launch(void* const* d_in, const int* in_sizes, int n_in,
                              void* d_out, int out_size, void* d_ws, size_t ws_size,
                              hipStream_t stream)
{
    const float* x      = (const float*)d_in[0];   // [T,H]
    const float* gate_w = (const float*)d_in[1];   // [E,H]
    const float* w_gate = (const float*)d_in[2];   // [E,H,I]
    const float* w_up   = (const float*)d_in[3];   // [E,H,I]
    const float* w_down = (const float*)d_in[4];   // [E,I,H]

    float* out        = (float*)d_out;                 // [T,H]
    float* logits_out = out + (size_t)T_TOK * H_DIM;   // [T,E]

    // Workspace layout
    char* ws = (char*)d_ws;
    int*   counts   = (int*)ws;                        // 8 ints
    int*   poff     = (int*)(ws + 64);                 // 8 ints (padded offsets)
    int*   tok_list = (int*)(ws + 1024);               // E*T ints (128 KB)
    float* w_list   = (float*)(ws + 1024 + E_NUM * T_TOK * 4);          // 128 KB
    int*   tslot    = (int*)(ws + 1024 + 2 * E_NUM * T_TOK * 4);        // 2*T ints (32 KB)
    int*   te       = (int*)(ws + 1024 + 2 * E_NUM * T_TOK * 4 + 2 * T_TOK * 4);   // T ints
    float2* tw      = (float2*)(ws + 1024 + 2 * E_NUM * T_TOK * 4 + 3 * T_TOK * 4); // T float2

    const size_t XG_ROWS = 9216;                       // 8192 + 8*128 padding
    const size_t OFF_XG = 1u << 20;
    const size_t OFF_HB = OFF_XG + XG_ROWS * H_DIM * 2;                 // xg: 18.9 MB
    const size_t OFF_WG = OFF_HB + XG_ROWS * I_DIM * 2;                 // hbuf: 37.7 MB
    const size_t OFF_WU = OFF_WG + (size_t)E_NUM * H_DIM * I_DIM * 2;   // 33.6 MB each
    const size_t OFF_WD = OFF_WU + (size_t)E_NUM * H_DIM * I_DIM * 2;

    unsigned short* xg   = (unsigned short*)(ws + OFF_XG);
    unsigned short* hbuf = (unsigned short*)(ws + OFF_HB);
    unsigned short* wgT  = (unsigned short*)(ws + OFF_WG);  // [E][I][H]
    unsigned short* wuT  = (unsigned short*)(ws + OFF_WU);  // [E][I][H]
    unsigned short* wdT  = (unsigned short*)(ws + OFF_WD);  // [E][H][I]
    // ybuf (f32 partials, 37.7 MB) ALIASES wgT/wuT — those are dead after mlp1,
    // and mlp2 (which writes ybuf) is stream-ordered after mlp1.
    float* ybuf = (float*)(ws + OFF_WG);

    router_kernel<<<T_TOK / 4, 256, 0, stream>>>(x, gate_w, logits_out, te, tw);
    scan_kernel<<<E_NUM, 256, 0, stream>>>(te, tw, counts, tok_list, w_list, tslot);
    offsets_kernel<<<1, 64, 0, stream>>>(counts, poff);

    dim3 gt1(I_DIM / 64, H_DIM / 64, E_NUM);
    transpose_cvt<<<gt1, 256, 0, stream>>>(w_gate, wgT, H_DIM, I_DIM);
    transpose_cvt<<<gt1, 256, 0, stream>>>(w_up,   wuT, H_DIM, I_DIM);
    dim3 gt2(H_DIM / 64, I_DIM / 64, E_NUM);
    transpose_cvt<<<gt2, 256, 0, stream>>>(w_down, wdT, I_DIM, H_DIM);

    gather_x<<<E_NUM * 128, 256, 0, stream>>>(x, counts, poff, tok_list, xg);

    dim3 g1(I_DIM / 128, T_TOK / 128, E_NUM);
    mlp1_kernel<<<g1, 512, 0, stream>>>(xg, wgT, wuT, counts, poff, hbuf);

    dim3 g2(H_DIM / 128, T_TOK / 128, E_NUM);
    mlp2_kernel<<<g2, 512, 0, stream>>>(hbuf, wdT, counts, poff, ybuf);

    combine_kernel<<<T_TOK, 256, 0, stream>>>(ybuf, poff, tslot, w_list, out);
}